// Round 9
// baseline (520.339 us; speedup 1.0000x reference)
//
#include <hip/hip_runtime.h>
#include <math.h>

// Problem: B=2, T=2048, E=2048, H=16, KVH=4 (GQA repeat 4), D=128, fp32 ref.
// Strategy: bf16 MFMA for all matmuls; fp32 softmax/bias/RoPE epilogues.
// Round 9 = round 8 resubmitted after audit (no bench last round):
// GEMM: double-buffered LDS, stage-ahead gload_lds (1 barrier per BK=32).
// Attention: spill-free T14 prefetch (named scalars), defer-max, deferred
// l-reduce, 40960B LDS / 4 blocks/CU, XOR-swizzled tiles.

typedef __bf16 bf16;
typedef __bf16 bf16x8 __attribute__((ext_vector_type(8)));
typedef __bf16 bf16x4 __attribute__((ext_vector_type(4)));
typedef __bf16 bf16x2 __attribute__((ext_vector_type(2)));
typedef float  f32x4  __attribute__((ext_vector_type(4)));

#define T_SEQ 2048
#define NE    2048
#define NH    16
#define NKVH  4
#define HD    128
#define KVD   512
#define OSCALE 0.022097086912079608f   // 1/sqrt(2048)

// async global(16B/lane) -> LDS (wave-uniform base + lane*16)
__device__ __forceinline__ void gload16(const void* g, void* l) {
  __builtin_amdgcn_global_load_lds(
      (const __attribute__((address_space(1))) void*)g,
      (__attribute__((address_space(3))) void*)l, 16, 0, 0);
}

// ---------------------------------------------------------------------------
// Prep 1: fp32 -> bf16 conversion of x, Wq, Wk, Wv, Wo (grid-stride, float4).
// ---------------------------------------------------------------------------
__global__ __launch_bounds__(256) void prep_convert(
    const float* __restrict__ x,  const float* __restrict__ wq,
    const float* __restrict__ wk, const float* __restrict__ wv,
    const float* __restrict__ wo,
    bf16* __restrict__ xb,  bf16* __restrict__ wqb, bf16* __restrict__ wkb,
    bf16* __restrict__ wvb, bf16* __restrict__ wob)
{
  const size_t total4 = (size_t)(8388608 + 4194304 + 1048576 + 1048576 + 4194304) / 4;
  for (size_t i = (size_t)blockIdx.x * blockDim.x + threadIdx.x; i < total4;
       i += (size_t)gridDim.x * blockDim.x) {
    size_t e = i * 4;
    const float* s; bf16* d; size_t off;
    if      (e <  8388608u) { s = x;  d = xb;  off = e; }
    else if (e < 12582912u) { s = wq; d = wqb; off = e -  8388608u; }
    else if (e < 13631488u) { s = wk; d = wkb; off = e - 12582912u; }
    else if (e < 14680064u) { s = wv; d = wvb; off = e - 13631488u; }
    else                    { s = wo; d = wob; off = e - 14680064u; }
    float4 v = *(const float4*)(s + off);
    bf16x4 o = {(bf16)v.x, (bf16)v.y, (bf16)v.z, (bf16)v.w};
    *(bf16x4*)(d + off) = o;
  }
}

// ---------------------------------------------------------------------------
// Prep 2: RoPE table rope[t*64+p] = (cos, sin)(t * 10000^(-p/64)), fp32.
// ---------------------------------------------------------------------------
__global__ __launch_bounds__(256) void rope_init(float2* __restrict__ rope)
{
  int i = blockIdx.x * 256 + threadIdx.x;     // 0..131071
  int t = i >> 6, p = i & 63;
  float invf = powf(10000.f, -(float)p * (1.f / 64.f));
  double frd = (double)((float)t * invf);
  rope[i] = make_float2((float)cos(frd), (float)sin(frd));
}

// ---------------------------------------------------------------------------
// bf16 MFMA GEMM mainloop: 128x128 tile, BK=32, double-buffered LDS,
// stage-ahead pipeline (gload_lds for tile k+1 issued BEFORE computing tile k;
// each __syncthreads drains vmcnt AFTER compute covered the load latency).
// K-loop unrolled x2 so buffer indices are compile-time constants.
// ---------------------------------------------------------------------------
__device__ __forceinline__ void mfma_gemm_128(
    const bf16* __restrict__ Ag,   // -> A[m0][0], row stride NE
    const bf16* __restrict__ Bg,   // -> W[n0][0], row stride NE
    f32x4 acc[4][4])
{
  __shared__ bf16 As[2][128][32];
  __shared__ bf16 Bs[2][128][32];
  const int tid  = threadIdx.x;
  const int wave = tid >> 6, lane = tid & 63;
  const int g = lane >> 4, c = lane & 15;
  const int wm = wave >> 1, wn = wave & 1;

  const f32x4 zf = {0.f, 0.f, 0.f, 0.f};
  #pragma unroll
  for (int mi = 0; mi < 4; ++mi)
    #pragma unroll
    for (int ni = 0; ni < 4; ++ni) acc[mi][ni] = zf;

  const int lr = lane >> 2;             // 0..15 row within wave's stripe
  const int lc = (lane & 3) * 8;        // element offset within row
  const bf16* aG0 = Ag + (size_t)(wave * 16 + lr) * NE + lc;
  const bf16* aG1 = aG0 + (size_t)64 * NE;
  const bf16* bG0 = Bg + (size_t)(wave * 16 + lr) * NE + lc;
  const bf16* bG1 = bG0 + (size_t)64 * NE;

#define G_STAGE(B, K) do {                                    \
    gload16(aG0 + (K), &As[B][wave * 16][0]);                 \
    gload16(aG1 + (K), &As[B][64 + wave * 16][0]);            \
    gload16(bG0 + (K), &Bs[B][wave * 16][0]);                 \
    gload16(bG1 + (K), &Bs[B][64 + wave * 16][0]);            \
  } while (0)

#define G_COMPUTE(B) do {                                     \
    bf16x8 af[4], bfr[4];                                     \
    _Pragma("unroll")                                         \
    for (int mi = 0; mi < 4; ++mi)                            \
      af[mi] = *(const bf16x8*)&As[B][wm * 64 + mi * 16 + c][g * 8]; \
    _Pragma("unroll")                                         \
    for (int ni = 0; ni < 4; ++ni)                            \
      bfr[ni] = *(const bf16x8*)&Bs[B][wn * 64 + ni * 16 + c][g * 8]; \
    _Pragma("unroll")                                         \
    for (int mi = 0; mi < 4; ++mi)                            \
      _Pragma("unroll")                                       \
      for (int ni = 0; ni < 4; ++ni)                          \
        acc[mi][ni] = __builtin_amdgcn_mfma_f32_16x16x32_bf16(\
            af[mi], bfr[ni], acc[mi][ni], 0, 0, 0);           \
  } while (0)

  G_STAGE(0, 0);
  __syncthreads();                      // tile 0 resident
  for (int k0 = 0; k0 < NE; k0 += 64) {
    G_STAGE(1, k0 + 32);                // in flight across compute(0)
    G_COMPUTE(0);
    __syncthreads();                    // drains stage(1); readers of buf0 done
    if (k0 + 64 < NE) G_STAGE(0, k0 + 64);
    G_COMPUTE(1);
    __syncthreads();
  }
#undef G_STAGE
#undef G_COMPUTE
}

// bijective XCD swizzle for nwg % 8 == 0 (m192: +10% when HBM/L2-bound)
__device__ __forceinline__ int xcd_swz(int bid, int nwg) {
  return (bid & 7) * (nwg >> 3) + (bid >> 3);
}

// ---------------------------------------------------------------------------
// Kernel A: QKV projection + bias + RoPE + scatter (epilogue unchanged).
// ---------------------------------------------------------------------------
__global__ __launch_bounds__(256) void qkv_mfma(
    const bf16* __restrict__ xb,  const bf16* __restrict__ wqb,
    const bf16* __restrict__ wkb, const bf16* __restrict__ wvb,
    const float* __restrict__ bq, const float* __restrict__ bk,
    const float* __restrict__ bv, const float2* __restrict__ rope,
    bf16* __restrict__ q_ws, bf16* __restrict__ k_ws, bf16* __restrict__ vT_ws)
{
  const int wid = xcd_swz(blockIdx.x, 768);
  const int n0 = (wid % 24) * 128;
  const int m0 = (wid / 24) * 128;
  int region; const bf16* Wp; const float* bp; int nl0;
  if (n0 < NE)            { region = 0; Wp = wqb; bp = bq; nl0 = n0; }
  else if (n0 < NE + KVD) { region = 1; Wp = wkb; bp = bk; nl0 = n0 - NE; }
  else                    { region = 2; Wp = wvb; bp = bv; nl0 = n0 - NE - KVD; }

  f32x4 acc[4][4];
  mfma_gemm_128(xb + (size_t)m0 * NE, Wp + (size_t)nl0 * NE, acc);

  const int tid = threadIdx.x, wave = tid >> 6, lane = tid & 63;
  const int g = lane >> 4, c = lane & 15;
  const int wm = wave >> 1, wn = wave & 1;
  const int bbase = m0 >> 11;                 // batch index (block-uniform)
  const int t0base = (m0 & (T_SEQ - 1)) + wm * 64;

  if (region < 2) {
    bf16* dst = (region == 0) ? q_ws : k_ws;
    const int nheads_stride = (region == 0) ? NH : NKVH;
    #pragma unroll
    for (int ni = 0; ni < 4; ++ni) {
      const int nloc = nl0 + wn * 64 + ni * 16 + c;
      const float bias = bp[nloc];
      const int d  = nloc & (HD - 1);
      const int p  = d >> 1;
      const int hh = nloc >> 7;
      const size_t base = ((size_t)bbase * nheads_stride + hh) * (size_t)T_SEQ * HD;
      #pragma unroll
      for (int mi = 0; mi < 4; ++mi) {
        #pragma unroll
        for (int r = 0; r < 4; ++r) {
          const int t = t0base + mi * 16 + g * 4 + r;
          float val = acc[mi][ni][r] + bias;
          float other = __shfl_xor(val, 1);       // even/odd column partner
          float2 cs = rope[t * 64 + p];
          float res = (c & 1) ? fmaf(other, cs.y, val * cs.x)
                              : fmaf(val, cs.x, -(other * cs.y));
          float rpair = __shfl_xor(res, 1);
          if (!(c & 1)) {
            bf16x2 pk = {(bf16)res, (bf16)rpair};
            *(bf16x2*)&dst[base + (size_t)t * HD + d] = pk;
          }
        }
      }
    }
  } else {
    #pragma unroll
    for (int ni = 0; ni < 4; ++ni) {
      const int nloc = nl0 + wn * 64 + ni * 16 + c;
      const float bias = bp[nloc];
      const int d  = nloc & (HD - 1);
      const int hh = nloc >> 7;
      const size_t vrow = ((size_t)bbase * NKVH + hh) * HD + d;  // [d][t] layout
      #pragma unroll
      for (int mi = 0; mi < 4; ++mi) {
        const int t0 = t0base + mi * 16 + g * 4;
        bf16x4 pk = {(bf16)(acc[mi][ni][0] + bias), (bf16)(acc[mi][ni][1] + bias),
                     (bf16)(acc[mi][ni][2] + bias), (bf16)(acc[mi][ni][3] + bias)};
        *(bf16x4*)&vT_ws[vrow * T_SEQ + t0] = pk;
      }
    }
  }
}

// ---------------------------------------------------------------------------
// Kernel B: causal flash attention. Spill-free T14 (named scalar prefetch
// regs, branch-free clamped next-tile address); defer-max; deferred l-reduce.
// ---------------------------------------------------------------------------
__global__ __launch_bounds__(256, 4) void attn_mfma(
    const bf16* __restrict__ q_ws, const bf16* __restrict__ k_ws,
    const bf16* __restrict__ vT_ws, bf16* __restrict__ o_ws)
{
  __shared__ __align__(16) char smem[40960];
  char* Ks = smem;            // [64][128] bf16, rows 256B, swizzled
  char* Vs = smem + 16384;    // [128][64] bf16, rows 128B, swizzled
  char* Ps = smem + 32768;    // [4 waves][16][64] bf16, rows 128B, swizzled

  const int tid = threadIdx.x, wave = tid >> 6, lane = tid & 63;
  const int g = lane >> 4, c = lane & 15;
  const int bid = blockIdx.x;
  const int u = bid & 31, v = bid >> 5;
  const int h = u & 15, b = u >> 4;
  const int qt = (v < 16) ? v : (47 - v);    // balanced under stride-256 dispatch
  const int kvh = h >> 2;

  const bf16* Qg = q_ws + (((size_t)b * NH + h) * T_SEQ + qt * 64 + wave * 16) * HD;
  const bf16* Kg = k_ws + ((size_t)b * NKVH + kvh) * (size_t)T_SEQ * HD;
  const bf16* Vg = vT_ws + ((size_t)b * NKVH + kvh) * (size_t)HD * T_SEQ;

  bf16x8 qf[4];                         // Q fragments live in registers
  #pragma unroll
  for (int kc = 0; kc < 4; ++kc)
    qf[kc] = *(const bf16x8*)(Qg + (size_t)c * HD + kc * 32 + g * 8);

  const f32x4 zf = {0.f, 0.f, 0.f, 0.f};
  f32x4 o_acc[8];
  #pragma unroll
  for (int i = 0; i < 8; ++i) o_acc[i] = zf;

  float m_run[4], l_part[4];
  #pragma unroll
  for (int r = 0; r < 4; ++r) { m_run[r] = -1e30f; l_part[r] = 0.f; }

  const int qrow_base = qt * 64 + wave * 16 + g * 4;
  const int ks_row = tid >> 4;               // 0..15 (+i*16)
  const int ks_cb  = (tid & 15) * 16;        // byte within 256B row
  const int vs_row = tid >> 3;               // 0..31 (+i*32)
  const int vs_cb  = (tid & 7) * 16;         // byte within 128B row
  const int swzc   = (c & 7) << 4;           // read-side swizzle for rows ≡ c
  const int swz_k  = ks_cb ^ ((ks_row & 7) << 4);  // +16k keeps row&7
  const int swz_v  = vs_cb ^ ((vs_row & 7) << 4);  // +32k keeps d&7
  const int ks_ce  = ks_cb >> 1;             // element offset
  const int vs_ce  = vs_cb >> 1;
  const int nkt = qt + 1;

  // T14 prologue: tile 0 into named scalar regs (no arrays -> no scratch)
  bf16x8 k0r = *(const bf16x8*)(Kg + (size_t)(ks_row     ) * HD + ks_ce);
  bf16x8 k1r = *(const bf16x8*)(Kg + (size_t)(ks_row + 16) * HD + ks_ce);
  bf16x8 k2r = *(const bf16x8*)(Kg + (size_t)(ks_row + 32) * HD + ks_ce);
  bf16x8 k3r = *(const bf16x8*)(Kg + (size_t)(ks_row + 48) * HD + ks_ce);
  bf16x8 v0r = *(const bf16x8*)(Vg + (size_t)(vs_row     ) * T_SEQ + vs_ce);
  bf16x8 v1r = *(const bf16x8*)(Vg + (size_t)(vs_row + 32) * T_SEQ + vs_ce);
  bf16x8 v2r = *(const bf16x8*)(Vg + (size_t)(vs_row + 64) * T_SEQ + vs_ce);
  bf16x8 v3r = *(const bf16x8*)(Vg + (size_t)(vs_row + 96) * T_SEQ + vs_ce);

  for (int kt = 0; kt < nkt; ++kt) {
    const int kb0 = kt * 64;
    __syncthreads();                    // prev iter's Ks/Vs readers done
    *(bf16x8*)(Ks + (ks_row     ) * 256 + swz_k) = k0r;
    *(bf16x8*)(Ks + (ks_row + 16) * 256 + swz_k) = k1r;
    *(bf16x8*)(Ks + (ks_row + 32) * 256 + swz_k) = k2r;
    *(bf16x8*)(Ks + (ks_row + 48) * 256 + swz_k) = k3r;
    *(bf16x8*)(Vs + (vs_row     ) * 128 + swz_v) = v0r;
    *(bf16x8*)(Vs + (vs_row + 32) * 128 + swz_v) = v1r;
    *(bf16x8*)(Vs + (vs_row + 64) * 128 + swz_v) = v2r;
    *(bf16x8*)(Vs + (vs_row + 96) * 128 + swz_v) = v3r;
    __syncthreads();                    // tiles visible

    // prefetch next tile (clamped -> branch-free; last iter re-reads, L2-warm)
    const int nb0 = (kt + 1 < nkt) ? (kb0 + 64) : kb0;
    k0r = *(const bf16x8*)(Kg + (size_t)(nb0 + ks_row     ) * HD + ks_ce);
    k1r = *(const bf16x8*)(Kg + (size_t)(nb0 + ks_row + 16) * HD + ks_ce);
    k2r = *(const bf16x8*)(Kg + (size_t)(nb0 + ks_row + 32) * HD + ks_ce);
    k3r = *(const bf16x8*)(Kg + (size_t)(nb0 + ks_row + 48) * HD + ks_ce);
    v0r = *(const bf16x8*)(Vg + (size_t)(vs_row     ) * T_SEQ + nb0 + vs_ce);
    v1r = *(const bf16x8*)(Vg + (size_t)(vs_row + 32) * T_SEQ + nb0 + vs_ce);
    v2r = *(const bf16x8*)(Vg + (size_t)(vs_row + 64) * T_SEQ + nb0 + vs_ce);
    v3r = *(const bf16x8*)(Vg + (size_t)(vs_row + 96) * T_SEQ + nb0 + vs_ce);

    // S = Q K^T (16 q-rows x 64 keys per wave)
    f32x4 s[4];
    #pragma unroll
    for (int cf = 0; cf < 4; ++cf) s[cf] = zf;
    __builtin_amdgcn_s_setprio(1);
    #pragma unroll
    for (int cf = 0; cf < 4; ++cf)
      #pragma unroll
      for (int kc = 0; kc < 4; ++kc) {
        bf16x8 kf = *(const bf16x8*)(Ks + (cf * 16 + c) * 256 +
                                     ((kc * 64 + g * 16) ^ swzc));
        s[cf] = __builtin_amdgcn_mfma_f32_16x16x32_bf16(qf[kc], kf, s[cf], 0, 0, 0);
      }
    __builtin_amdgcn_s_setprio(0);

    if (kt == qt) {                     // causal mask (diagonal tile only)
      #pragma unroll
      for (int cf = 0; cf < 4; ++cf) {
        int key = kb0 + cf * 16 + c;
        #pragma unroll
        for (int r = 0; r < 4; ++r)
          if (key > qrow_base + r) s[cf][r] = -1e30f;
      }
    }

    // row max (reduce over 16 c-lanes)
    float pmax[4];
    #pragma unroll
    for (int r = 0; r < 4; ++r) {
      float m2 = fmaxf(fmaxf(s[0][r], s[1][r]), fmaxf(s[2][r], s[3][r]));
      m2 = fmaxf(m2, __shfl_xor(m2, 1));
      m2 = fmaxf(m2, __shfl_xor(m2, 2));
      m2 = fmaxf(m2, __shfl_xor(m2, 4));
      m2 = fmaxf(m2, __shfl_xor(m2, 8));
      pmax[r] = m2;
    }
    // T13 defer-max: only rescale when some row's max grew past THR=8
    int ok = (pmax[0] <= m_run[0] + 8.f) & (pmax[1] <= m_run[1] + 8.f) &
             (pmax[2] <= m_run[2] + 8.f) & (pmax[3] <= m_run[3] + 8.f);
    if (!__all(ok)) {
      #pragma unroll
      for (int r = 0; r < 4; ++r) {
        float mn = fmaxf(m_run[r], pmax[r]);
        float corr = __expf(m_run[r] - mn);
        m_run[r] = mn;
        l_part[r] *= corr;
        #pragma unroll
        for (int d0 = 0; d0 < 8; ++d0) o_acc[d0][r] *= corr;
      }
    }
    // exponentials + per-lane partial row sums (cross-lane reduce deferred)
    #pragma unroll
    for (int cf = 0; cf < 4; ++cf)
      #pragma unroll
      for (int r = 0; r < 4; ++r) {
        float p = __expf(s[cf][r] - m_run[r]);
        s[cf][r] = p;
        l_part[r] += p;
      }

    // P -> LDS bf16 (wave-private strip)
    char* Pw = Ps + wave * 2048;
    #pragma unroll
    for (int cf = 0; cf < 4; ++cf)
      #pragma unroll
      for (int r = 0; r < 4; ++r) {
        int row = g * 4 + r;
        *(bf16*)(Pw + row * 128 + (((cf * 16 + c) * 2) ^ ((row & 7) << 4))) =
            (bf16)s[cf][r];
      }

    // O += P V  (A = P strip, B = V^T tile; keys split 0..31 / 32..63)
    bf16x8 pa0 = *(const bf16x8*)(Pw + c * 128 + ((g * 16) ^ swzc));
    bf16x8 pa1 = *(const bf16x8*)(Pw + c * 128 + ((64 + g * 16) ^ swzc));
    __builtin_amdgcn_s_setprio(1);
    #pragma unroll
    for (int d0 = 0; d0 < 8; ++d0) {
      bf16x8 v0 = *(const bf16x8*)(Vs + (d0 * 16 + c) * 128 + ((g * 16) ^ swzc));
      bf16x8 v1 = *(const bf16x8*)(Vs + (d0 * 16 + c) * 128 + ((64 + g * 16) ^ swzc));
      o_acc[d0] = __builtin_amdgcn_mfma_f32_16x16x32_bf16(pa0, v0, o_acc[d0], 0, 0, 0);
      o_acc[d0] = __builtin_amdgcn_mfma_f32_16x16x32_bf16(pa1, v1, o_acc[d0], 0, 0, 0);
    }
    __builtin_amdgcn_s_setprio(0);
  }

  // final l reduce (once) then scale+store
  float f[4];
  #pragma unroll
  for (int r = 0; r < 4; ++r) {
    float lt = l_part[r];
    lt += __shfl_xor(lt, 1); lt += __shfl_xor(lt, 2);
    lt += __shfl_xor(lt, 4); lt += __shfl_xor(lt, 8);
    f[r] = OSCALE / lt;
  }
  #pragma unroll
  for (int d0 = 0; d0 < 8; ++d0)
    #pragma unroll
    for (int r = 0; r < 4; ++r) {
      float val = o_acc[d0][r] * f[r];
      float pv = __shfl_xor(val, 1);
      if (!(c & 1)) {
        bf16x2 pk = {(bf16)val, (bf16)pv};
        size_t row = (size_t)b * T_SEQ + qt * 64 + wave * 16 + g * 4 + r;
        int col = h * HD + d0 * 16 + c;
        *(bf16x2*)&o_ws[row * NE + col] = pk;
      }
    }
}

// ---------------------------------------------------------------------------
// Kernel C: out = O @ Wo^T + bo (epilogue unchanged).
// ---------------------------------------------------------------------------
__global__ __launch_bounds__(256) void out_proj_mfma(
    const bf16* __restrict__ ob, const bf16* __restrict__ wob,
    const float* __restrict__ bo, float* __restrict__ out)
{
  const int wid = xcd_swz(blockIdx.x, 512);
  const int n0 = (wid % 16) * 128;
  const int m0 = (wid / 16) * 128;
  f32x4 acc[4][4];
  mfma_gemm_128(ob + (size_t)m0 * NE, wob + (size_t)n0 * NE, acc);

  const int tid = threadIdx.x, wave = tid >> 6, lane = tid & 63;
  const int g = lane >> 4, c = lane & 15;
  const int wm = wave >> 1, wn = wave & 1;
  #pragma unroll
  for (int ni = 0; ni < 4; ++ni) {
    const int n = n0 + wn * 64 + ni * 16 + c;
    const float bias = bo[n];
    #pragma unroll
    for (int mi = 0; mi < 4; ++mi)
      #pragma unroll
      for (int r = 0; r < 4; ++r) {
        const int m = m0 + wm * 64 + mi * 16 + g * 4 + r;
        out[(size_t)m * NE + n] = acc[mi][ni][r] + bias;
      }
  }
}

// ---------------------------------------------------------------------------
extern "C" void kernel_launch(void* const* d_in, const int* in_sizes, int n_in,
                              void* d_out, int out_size, void* d_ws, size_t ws_size,
                              hipStream_t stream)
{
  const float* x  = (const float*)d_in[0];
  const float* Wq = (const float*)d_in[1];
  const float* bq = (const float*)d_in[2];
  const float* Wk = (const float*)d_in[3];
  const float* bk = (const float*)d_in[4];
  const float* Wv = (const float*)d_in[5];
  const float* bv = (const float*)d_in[6];
  const float* Wo = (const float*)d_in[7];
  const float* bo = (const float*)d_in[8];
  float* out = (float*)d_out;

  // ws carve (bf16 elements unless noted); total ~81 MB
  bf16* xb    = (bf16*)d_ws;                 // 8388608   x  [4096][2048]
  bf16* wqb   = xb    + 8388608;             // 4194304   Wq [2048][2048]
  bf16* wkb   = wqb   + 4194304;             // 1048576   Wk [512][2048]
  bf16* wvb   = wkb   + 1048576;             // 1048576   Wv [512][2048]
  bf16* wob   = wvb   + 1048576;             // 4194304   Wo [2048][2048]
  bf16* q_ws  = wob   + 4194304;             // 8388608   [2][16][2048][128]
  bf16* k_ws  = q_ws  + 8388608;             // 2097152   [2][4][2048][128]
  bf16* vT_ws = k_ws  + 2097152;             // 2097152   [2][4][128][2048]
  bf16* o_ws  = vT_ws + 2097152;             // 8388608   [4096][2048]
  float2* rope = (float2*)(o_ws + 8388608);  // 131072 float2 (1 MB)

  prep_convert<<<2048, 256, 0, stream>>>(x, Wq, Wk, Wv, Wo, xb, wqb, wkb, wvb, wob);
  rope_init<<<512, 256, 0, stream>>>(rope);
  qkv_mfma<<<768, 256, 0, stream>>>(xb, wqb, wkb, wvb, bq, bk, bv, rope,
                                    q_ws, k_ws, vT_ws);
  attn_mfma<<<1024, 256, 0, stream>>>(q_ws, k_ws, vT_ws, o_ws);
  out_proj_mfma<<<512, 256, 0, stream>>>(o_ws, wob, bo, out);
}

// Round 10
// 409.078 us; speedup vs baseline: 1.2720x; 1.2720x over previous
//
#include <hip/hip_runtime.h>
#include <math.h>

// Problem: B=2, T=2048, E=2048, H=16, KVH=4 (GQA repeat 4), D=128, fp32 ref.
// Strategy: bf16 MFMA for all matmuls; fp32 softmax/bias/RoPE epilogues.
// Round 10: ONE change vs round 9 — attn __launch_bounds__(256,4) -> (256).
// The ",4" forced VGPR=64 and spilled ~150 live regs to scratch; rocprof
// showed 100+MB of scratch traffic dominating attn time in rounds 6-9.

typedef __bf16 bf16;
typedef __bf16 bf16x8 __attribute__((ext_vector_type(8)));
typedef __bf16 bf16x4 __attribute__((ext_vector_type(4)));
typedef __bf16 bf16x2 __attribute__((ext_vector_type(2)));
typedef float  f32x4  __attribute__((ext_vector_type(4)));

#define T_SEQ 2048
#define NE    2048
#define NH    16
#define NKVH  4
#define HD    128
#define KVD   512
#define OSCALE 0.022097086912079608f   // 1/sqrt(2048)

// async global(16B/lane) -> LDS (wave-uniform base + lane*16)
__device__ __forceinline__ void gload16(const void* g, void* l) {
  __builtin_amdgcn_global_load_lds(
      (const __attribute__((address_space(1))) void*)g,
      (__attribute__((address_space(3))) void*)l, 16, 0, 0);
}

// ---------------------------------------------------------------------------
// Prep 1: fp32 -> bf16 conversion of x, Wq, Wk, Wv, Wo (grid-stride, float4).
// ---------------------------------------------------------------------------
__global__ __launch_bounds__(256) void prep_convert(
    const float* __restrict__ x,  const float* __restrict__ wq,
    const float* __restrict__ wk, const float* __restrict__ wv,
    const float* __restrict__ wo,
    bf16* __restrict__ xb,  bf16* __restrict__ wqb, bf16* __restrict__ wkb,
    bf16* __restrict__ wvb, bf16* __restrict__ wob)
{
  const size_t total4 = (size_t)(8388608 + 4194304 + 1048576 + 1048576 + 4194304) / 4;
  for (size_t i = (size_t)blockIdx.x * blockDim.x + threadIdx.x; i < total4;
       i += (size_t)gridDim.x * blockDim.x) {
    size_t e = i * 4;
    const float* s; bf16* d; size_t off;
    if      (e <  8388608u) { s = x;  d = xb;  off = e; }
    else if (e < 12582912u) { s = wq; d = wqb; off = e -  8388608u; }
    else if (e < 13631488u) { s = wk; d = wkb; off = e - 12582912u; }
    else if (e < 14680064u) { s = wv; d = wvb; off = e - 13631488u; }
    else                    { s = wo; d = wob; off = e - 14680064u; }
    float4 v = *(const float4*)(s + off);
    bf16x4 o = {(bf16)v.x, (bf16)v.y, (bf16)v.z, (bf16)v.w};
    *(bf16x4*)(d + off) = o;
  }
}

// ---------------------------------------------------------------------------
// Prep 2: RoPE table rope[t*64+p] = (cos, sin)(t * 10000^(-p/64)), fp32.
// ---------------------------------------------------------------------------
__global__ __launch_bounds__(256) void rope_init(float2* __restrict__ rope)
{
  int i = blockIdx.x * 256 + threadIdx.x;     // 0..131071
  int t = i >> 6, p = i & 63;
  float invf = powf(10000.f, -(float)p * (1.f / 64.f));
  double frd = (double)((float)t * invf);
  rope[i] = make_float2((float)cos(frd), (float)sin(frd));
}

// ---------------------------------------------------------------------------
// bf16 MFMA GEMM mainloop: 128x128 tile, BK=32, double-buffered LDS,
// stage-ahead pipeline (gload_lds for tile k+1 issued BEFORE computing tile k).
// ---------------------------------------------------------------------------
__device__ __forceinline__ void mfma_gemm_128(
    const bf16* __restrict__ Ag,   // -> A[m0][0], row stride NE
    const bf16* __restrict__ Bg,   // -> W[n0][0], row stride NE
    f32x4 acc[4][4])
{
  __shared__ bf16 As[2][128][32];
  __shared__ bf16 Bs[2][128][32];
  const int tid  = threadIdx.x;
  const int wave = tid >> 6, lane = tid & 63;
  const int g = lane >> 4, c = lane & 15;
  const int wm = wave >> 1, wn = wave & 1;

  const f32x4 zf = {0.f, 0.f, 0.f, 0.f};
  #pragma unroll
  for (int mi = 0; mi < 4; ++mi)
    #pragma unroll
    for (int ni = 0; ni < 4; ++ni) acc[mi][ni] = zf;

  const int lr = lane >> 2;             // 0..15 row within wave's stripe
  const int lc = (lane & 3) * 8;        // element offset within row
  const bf16* aG0 = Ag + (size_t)(wave * 16 + lr) * NE + lc;
  const bf16* aG1 = aG0 + (size_t)64 * NE;
  const bf16* bG0 = Bg + (size_t)(wave * 16 + lr) * NE + lc;
  const bf16* bG1 = bG0 + (size_t)64 * NE;

#define G_STAGE(B, K) do {                                    \
    gload16(aG0 + (K), &As[B][wave * 16][0]);                 \
    gload16(aG1 + (K), &As[B][64 + wave * 16][0]);            \
    gload16(bG0 + (K), &Bs[B][wave * 16][0]);                 \
    gload16(bG1 + (K), &Bs[B][64 + wave * 16][0]);            \
  } while (0)

#define G_COMPUTE(B) do {                                     \
    bf16x8 af[4], bfr[4];                                     \
    _Pragma("unroll")                                         \
    for (int mi = 0; mi < 4; ++mi)                            \
      af[mi] = *(const bf16x8*)&As[B][wm * 64 + mi * 16 + c][g * 8]; \
    _Pragma("unroll")                                         \
    for (int ni = 0; ni < 4; ++ni)                            \
      bfr[ni] = *(const bf16x8*)&Bs[B][wn * 64 + ni * 16 + c][g * 8]; \
    _Pragma("unroll")                                         \
    for (int mi = 0; mi < 4; ++mi)                            \
      _Pragma("unroll")                                       \
      for (int ni = 0; ni < 4; ++ni)                          \
        acc[mi][ni] = __builtin_amdgcn_mfma_f32_16x16x32_bf16(\
            af[mi], bfr[ni], acc[mi][ni], 0, 0, 0);           \
  } while (0)

  G_STAGE(0, 0);
  __syncthreads();                      // tile 0 resident
  for (int k0 = 0; k0 < NE; k0 += 64) {
    G_STAGE(1, k0 + 32);                // in flight across compute(0)
    G_COMPUTE(0);
    __syncthreads();                    // drains stage(1); readers of buf0 done
    if (k0 + 64 < NE) G_STAGE(0, k0 + 64);
    G_COMPUTE(1);
    __syncthreads();
  }
#undef G_STAGE
#undef G_COMPUTE
}

// bijective XCD swizzle for nwg % 8 == 0 (m192: +10% when HBM/L2-bound)
__device__ __forceinline__ int xcd_swz(int bid, int nwg) {
  return (bid & 7) * (nwg >> 3) + (bid >> 3);
}

// ---------------------------------------------------------------------------
// Kernel A: QKV projection + bias + RoPE + scatter (unchanged).
// ---------------------------------------------------------------------------
__global__ __launch_bounds__(256) void qkv_mfma(
    const bf16* __restrict__ xb,  const bf16* __restrict__ wqb,
    const bf16* __restrict__ wkb, const bf16* __restrict__ wvb,
    const float* __restrict__ bq, const float* __restrict__ bk,
    const float* __restrict__ bv, const float2* __restrict__ rope,
    bf16* __restrict__ q_ws, bf16* __restrict__ k_ws, bf16* __restrict__ vT_ws)
{
  const int wid = xcd_swz(blockIdx.x, 768);
  const int n0 = (wid % 24) * 128;
  const int m0 = (wid / 24) * 128;
  int region; const bf16* Wp; const float* bp; int nl0;
  if (n0 < NE)            { region = 0; Wp = wqb; bp = bq; nl0 = n0; }
  else if (n0 < NE + KVD) { region = 1; Wp = wkb; bp = bk; nl0 = n0 - NE; }
  else                    { region = 2; Wp = wvb; bp = bv; nl0 = n0 - NE - KVD; }

  f32x4 acc[4][4];
  mfma_gemm_128(xb + (size_t)m0 * NE, Wp + (size_t)nl0 * NE, acc);

  const int tid = threadIdx.x, wave = tid >> 6, lane = tid & 63;
  const int g = lane >> 4, c = lane & 15;
  const int wm = wave >> 1, wn = wave & 1;
  const int bbase = m0 >> 11;                 // batch index (block-uniform)
  const int t0base = (m0 & (T_SEQ - 1)) + wm * 64;

  if (region < 2) {
    bf16* dst = (region == 0) ? q_ws : k_ws;
    const int nheads_stride = (region == 0) ? NH : NKVH;
    #pragma unroll
    for (int ni = 0; ni < 4; ++ni) {
      const int nloc = nl0 + wn * 64 + ni * 16 + c;
      const float bias = bp[nloc];
      const int d  = nloc & (HD - 1);
      const int p  = d >> 1;
      const int hh = nloc >> 7;
      const size_t base = ((size_t)bbase * nheads_stride + hh) * (size_t)T_SEQ * HD;
      #pragma unroll
      for (int mi = 0; mi < 4; ++mi) {
        #pragma unroll
        for (int r = 0; r < 4; ++r) {
          const int t = t0base + mi * 16 + g * 4 + r;
          float val = acc[mi][ni][r] + bias;
          float other = __shfl_xor(val, 1);       // even/odd column partner
          float2 cs = rope[t * 64 + p];
          float res = (c & 1) ? fmaf(other, cs.y, val * cs.x)
                              : fmaf(val, cs.x, -(other * cs.y));
          float rpair = __shfl_xor(res, 1);
          if (!(c & 1)) {
            bf16x2 pk = {(bf16)res, (bf16)rpair};
            *(bf16x2*)&dst[base + (size_t)t * HD + d] = pk;
          }
        }
      }
    }
  } else {
    #pragma unroll
    for (int ni = 0; ni < 4; ++ni) {
      const int nloc = nl0 + wn * 64 + ni * 16 + c;
      const float bias = bp[nloc];
      const int d  = nloc & (HD - 1);
      const int hh = nloc >> 7;
      const size_t vrow = ((size_t)bbase * NKVH + hh) * HD + d;  // [d][t] layout
      #pragma unroll
      for (int mi = 0; mi < 4; ++mi) {
        const int t0 = t0base + mi * 16 + g * 4;
        bf16x4 pk = {(bf16)(acc[mi][ni][0] + bias), (bf16)(acc[mi][ni][1] + bias),
                     (bf16)(acc[mi][ni][2] + bias), (bf16)(acc[mi][ni][3] + bias)};
        *(bf16x4*)&vT_ws[vrow * T_SEQ + t0] = pk;
      }
    }
  }
}

// ---------------------------------------------------------------------------
// Kernel B: causal flash attention. Round 10: NO occupancy bound (the ",4"
// forced VGPR=64 -> ~100MB scratch traffic). Structure otherwise = round 9.
// ---------------------------------------------------------------------------
__global__ __launch_bounds__(256) void attn_mfma(
    const bf16* __restrict__ q_ws, const bf16* __restrict__ k_ws,
    const bf16* __restrict__ vT_ws, bf16* __restrict__ o_ws)
{
  __shared__ __align__(16) char smem[40960];
  char* Ks = smem;            // [64][128] bf16, rows 256B, swizzled
  char* Vs = smem + 16384;    // [128][64] bf16, rows 128B, swizzled
  char* Ps = smem + 32768;    // [4 waves][16][64] bf16, rows 128B, swizzled

  const int tid = threadIdx.x, wave = tid >> 6, lane = tid & 63;
  const int g = lane >> 4, c = lane & 15;
  const int bid = blockIdx.x;
  const int u = bid & 31, v = bid >> 5;
  const int h = u & 15, b = u >> 4;
  const int qt = (v < 16) ? v : (47 - v);    // balanced under stride-256 dispatch
  const int kvh = h >> 2;

  const bf16* Qg = q_ws + (((size_t)b * NH + h) * T_SEQ + qt * 64 + wave * 16) * HD;
  const bf16* Kg = k_ws + ((size_t)b * NKVH + kvh) * (size_t)T_SEQ * HD;
  const bf16* Vg = vT_ws + ((size_t)b * NKVH + kvh) * (size_t)HD * T_SEQ;

  bf16x8 qf[4];                         // Q fragments live in registers
  #pragma unroll
  for (int kc = 0; kc < 4; ++kc)
    qf[kc] = *(const bf16x8*)(Qg + (size_t)c * HD + kc * 32 + g * 8);

  const f32x4 zf = {0.f, 0.f, 0.f, 0.f};
  f32x4 o_acc[8];
  #pragma unroll
  for (int i = 0; i < 8; ++i) o_acc[i] = zf;

  float m_run[4], l_part[4];
  #pragma unroll
  for (int r = 0; r < 4; ++r) { m_run[r] = -1e30f; l_part[r] = 0.f; }

  const int qrow_base = qt * 64 + wave * 16 + g * 4;
  const int ks_row = tid >> 4;               // 0..15 (+i*16)
  const int ks_cb  = (tid & 15) * 16;        // byte within 256B row
  const int vs_row = tid >> 3;               // 0..31 (+i*32)
  const int vs_cb  = (tid & 7) * 16;         // byte within 128B row
  const int swzc   = (c & 7) << 4;           // read-side swizzle for rows ≡ c
  const int swz_k  = ks_cb ^ ((ks_row & 7) << 4);  // +16k keeps row&7
  const int swz_v  = vs_cb ^ ((vs_row & 7) << 4);  // +32k keeps d&7
  const int ks_ce  = ks_cb >> 1;             // element offset
  const int vs_ce  = vs_cb >> 1;
  const int nkt = qt + 1;

  // T14 prologue: tile 0 into named scalar regs
  bf16x8 k0r = *(const bf16x8*)(Kg + (size_t)(ks_row     ) * HD + ks_ce);
  bf16x8 k1r = *(const bf16x8*)(Kg + (size_t)(ks_row + 16) * HD + ks_ce);
  bf16x8 k2r = *(const bf16x8*)(Kg + (size_t)(ks_row + 32) * HD + ks_ce);
  bf16x8 k3r = *(const bf16x8*)(Kg + (size_t)(ks_row + 48) * HD + ks_ce);
  bf16x8 v0r = *(const bf16x8*)(Vg + (size_t)(vs_row     ) * T_SEQ + vs_ce);
  bf16x8 v1r = *(const bf16x8*)(Vg + (size_t)(vs_row + 32) * T_SEQ + vs_ce);
  bf16x8 v2r = *(const bf16x8*)(Vg + (size_t)(vs_row + 64) * T_SEQ + vs_ce);
  bf16x8 v3r = *(const bf16x8*)(Vg + (size_t)(vs_row + 96) * T_SEQ + vs_ce);

  for (int kt = 0; kt < nkt; ++kt) {
    const int kb0 = kt * 64;
    __syncthreads();                    // prev iter's Ks/Vs readers done
    *(bf16x8*)(Ks + (ks_row     ) * 256 + swz_k) = k0r;
    *(bf16x8*)(Ks + (ks_row + 16) * 256 + swz_k) = k1r;
    *(bf16x8*)(Ks + (ks_row + 32) * 256 + swz_k) = k2r;
    *(bf16x8*)(Ks + (ks_row + 48) * 256 + swz_k) = k3r;
    *(bf16x8*)(Vs + (vs_row     ) * 128 + swz_v) = v0r;
    *(bf16x8*)(Vs + (vs_row + 32) * 128 + swz_v) = v1r;
    *(bf16x8*)(Vs + (vs_row + 64) * 128 + swz_v) = v2r;
    *(bf16x8*)(Vs + (vs_row + 96) * 128 + swz_v) = v3r;
    __syncthreads();                    // tiles visible

    // prefetch next tile (clamped -> branch-free; last iter re-reads, L2-warm)
    const int nb0 = (kt + 1 < nkt) ? (kb0 + 64) : kb0;
    k0r = *(const bf16x8*)(Kg + (size_t)(nb0 + ks_row     ) * HD + ks_ce);
    k1r = *(const bf16x8*)(Kg + (size_t)(nb0 + ks_row + 16) * HD + ks_ce);
    k2r = *(const bf16x8*)(Kg + (size_t)(nb0 + ks_row + 32) * HD + ks_ce);
    k3r = *(const bf16x8*)(Kg + (size_t)(nb0 + ks_row + 48) * HD + ks_ce);
    v0r = *(const bf16x8*)(Vg + (size_t)(vs_row     ) * T_SEQ + nb0 + vs_ce);
    v1r = *(const bf16x8*)(Vg + (size_t)(vs_row + 32) * T_SEQ + nb0 + vs_ce);
    v2r = *(const bf16x8*)(Vg + (size_t)(vs_row + 64) * T_SEQ + nb0 + vs_ce);
    v3r = *(const bf16x8*)(Vg + (size_t)(vs_row + 96) * T_SEQ + nb0 + vs_ce);

    // S = Q K^T (16 q-rows x 64 keys per wave)
    f32x4 s[4];
    #pragma unroll
    for (int cf = 0; cf < 4; ++cf) s[cf] = zf;
    __builtin_amdgcn_s_setprio(1);
    #pragma unroll
    for (int cf = 0; cf < 4; ++cf)
      #pragma unroll
      for (int kc = 0; kc < 4; ++kc) {
        bf16x8 kf = *(const bf16x8*)(Ks + (cf * 16 + c) * 256 +
                                     ((kc * 64 + g * 16) ^ swzc));
        s[cf] = __builtin_amdgcn_mfma_f32_16x16x32_bf16(qf[kc], kf, s[cf], 0, 0, 0);
      }
    __builtin_amdgcn_s_setprio(0);

    if (kt == qt) {                     // causal mask (diagonal tile only)
      #pragma unroll
      for (int cf = 0; cf < 4; ++cf) {
        int key = kb0 + cf * 16 + c;
        #pragma unroll
        for (int r = 0; r < 4; ++r)
          if (key > qrow_base + r) s[cf][r] = -1e30f;
      }
    }

    // row max (reduce over 16 c-lanes)
    float pmax[4];
    #pragma unroll
    for (int r = 0; r < 4; ++r) {
      float m2 = fmaxf(fmaxf(s[0][r], s[1][r]), fmaxf(s[2][r], s[3][r]));
      m2 = fmaxf(m2, __shfl_xor(m2, 1));
      m2 = fmaxf(m2, __shfl_xor(m2, 2));
      m2 = fmaxf(m2, __shfl_xor(m2, 4));
      m2 = fmaxf(m2, __shfl_xor(m2, 8));
      pmax[r] = m2;
    }
    // T13 defer-max: only rescale when some row's max grew past THR=8
    int ok = (pmax[0] <= m_run[0] + 8.f) & (pmax[1] <= m_run[1] + 8.f) &
             (pmax[2] <= m_run[2] + 8.f) & (pmax[3] <= m_run[3] + 8.f);
    if (!__all(ok)) {
      #pragma unroll
      for (int r = 0; r < 4; ++r) {
        float mn = fmaxf(m_run[r], pmax[r]);
        float corr = __expf(m_run[r] - mn);
        m_run[r] = mn;
        l_part[r] *= corr;
        #pragma unroll
        for (int d0 = 0; d0 < 8; ++d0) o_acc[d0][r] *= corr;
      }
    }
    // exponentials + per-lane partial row sums (cross-lane reduce deferred)
    #pragma unroll
    for (int cf = 0; cf < 4; ++cf)
      #pragma unroll
      for (int r = 0; r < 4; ++r) {
        float p = __expf(s[cf][r] - m_run[r]);
        s[cf][r] = p;
        l_part[r] += p;
      }

    // P -> LDS bf16 (wave-private strip)
    char* Pw = Ps + wave * 2048;
    #pragma unroll
    for (int cf = 0; cf < 4; ++cf)
      #pragma unroll
      for (int r = 0; r < 4; ++r) {
        int row = g * 4 + r;
        *(bf16*)(Pw + row * 128 + (((cf * 16 + c) * 2) ^ ((row & 7) << 4))) =
            (bf16)s[cf][r];
      }

    // O += P V  (A = P strip, B = V^T tile; keys split 0..31 / 32..63)
    bf16x8 pa0 = *(const bf16x8*)(Pw + c * 128 + ((g * 16) ^ swzc));
    bf16x8 pa1 = *(const bf16x8*)(Pw + c * 128 + ((64 + g * 16) ^ swzc));
    __builtin_amdgcn_s_setprio(1);
    #pragma unroll
    for (int d0 = 0; d0 < 8; ++d0) {
      bf16x8 v0 = *(const bf16x8*)(Vs + (d0 * 16 + c) * 128 + ((g * 16) ^ swzc));
      bf16x8 v1 = *(const bf16x8*)(Vs + (d0 * 16 + c) * 128 + ((64 + g * 16) ^ swzc));
      o_acc[d0] = __builtin_amdgcn_mfma_f32_16x16x32_bf16(pa0, v0, o_acc[d0], 0, 0, 0);
      o_acc[d0] = __builtin_amdgcn_mfma_f32_16x16x32_bf16(pa1, v1, o_acc[d0], 0, 0, 0);
    }
    __builtin_amdgcn_s_setprio(0);
  }

  // final l reduce (once) then scale+store
  float f[4];
  #pragma unroll
  for (int r = 0; r < 4; ++r) {
    float lt = l_part[r];
    lt += __shfl_xor(lt, 1); lt += __shfl_xor(lt, 2);
    lt += __shfl_xor(lt, 4); lt += __shfl_xor(lt, 8);
    f[r] = OSCALE / lt;
  }
  #pragma unroll
  for (int d0 = 0; d0 < 8; ++d0)
    #pragma unroll
    for (int r = 0; r < 4; ++r) {
      float val = o_acc[d0][r] * f[r];
      float pv = __shfl_xor(val, 1);
      if (!(c & 1)) {
        bf16x2 pk = {(bf16)val, (bf16)pv};
        size_t row = (size_t)b * T_SEQ + qt * 64 + wave * 16 + g * 4 + r;
        int col = h * HD + d0 * 16 + c;
        *(bf16x2*)&o_ws[row * NE + col] = pk;
      }
    }
}

// ---------------------------------------------------------------------------
// Kernel C: out = O @ Wo^T + bo (unchanged).
// ---------------------------------------------------------------------------
__global__ __launch_bounds__(256) void out_proj_mfma(
    const bf16* __restrict__ ob, const bf16* __restrict__ wob,
    const float* __restrict__ bo, float* __restrict__ out)
{
  const int wid = xcd_swz(blockIdx.x, 512);
  const int n0 = (wid % 16) * 128;
  const int m0 = (wid / 16) * 128;
  f32x4 acc[4][4];
  mfma_gemm_128(ob + (size_t)m0 * NE, wob + (size_t)n0 * NE, acc);

  const int tid = threadIdx.x, wave = tid >> 6, lane = tid & 63;
  const int g = lane >> 4, c = lane & 15;
  const int wm = wave >> 1, wn = wave & 1;
  #pragma unroll
  for (int ni = 0; ni < 4; ++ni) {
    const int n = n0 + wn * 64 + ni * 16 + c;
    const float bias = bo[n];
    #pragma unroll
    for (int mi = 0; mi < 4; ++mi)
      #pragma unroll
      for (int r = 0; r < 4; ++r) {
        const int m = m0 + wm * 64 + mi * 16 + g * 4 + r;
        out[(size_t)m * NE + n] = acc[mi][ni][r] + bias;
      }
  }
}

// ---------------------------------------------------------------------------
extern "C" void kernel_launch(void* const* d_in, const int* in_sizes, int n_in,
                              void* d_out, int out_size, void* d_ws, size_t ws_size,
                              hipStream_t stream)
{
  const float* x  = (const float*)d_in[0];
  const float* Wq = (const float*)d_in[1];
  const float* bq = (const float*)d_in[2];
  const float* Wk = (const float*)d_in[3];
  const float* bk = (const float*)d_in[4];
  const float* Wv = (const float*)d_in[5];
  const float* bv = (const float*)d_in[6];
  const float* Wo = (const float*)d_in[7];
  const float* bo = (const float*)d_in[8];
  float* out = (float*)d_out;

  // ws carve (bf16 elements unless noted); total ~81 MB
  bf16* xb    = (bf16*)d_ws;                 // 8388608   x  [4096][2048]
  bf16* wqb   = xb    + 8388608;             // 4194304   Wq [2048][2048]
  bf16* wkb   = wqb   + 4194304;             // 1048576   Wk [512][2048]
  bf16* wvb   = wkb   + 1048576;             // 1048576   Wv [512][2048]
  bf16* wob   = wvb   + 1048576;             // 4194304   Wo [2048][2048]
  bf16* q_ws  = wob   + 4194304;             // 8388608   [2][16][2048][128]
  bf16* k_ws  = q_ws  + 8388608;             // 2097152   [2][4][2048][128]
  bf16* vT_ws = k_ws  + 2097152;             // 2097152   [2][4][128][2048]
  bf16* o_ws  = vT_ws + 2097152;             // 8388608   [4096][2048]
  float2* rope = (float2*)(o_ws + 8388608);  // 131072 float2 (1 MB)

  prep_convert<<<2048, 256, 0, stream>>>(x, Wq, Wk, Wv, Wo, xb, wqb, wkb, wvb, wob);
  rope_init<<<512, 256, 0, stream>>>(rope);
  qkv_mfma<<<768, 256, 0, stream>>>(xb, wqb, wkb, wvb, bq, bk, bv, rope,
                                    q_ws, k_ws, vT_ws);
  attn_mfma<<<1024, 256, 0, stream>>>(q_ws, k_ws, vT_ws, o_ws);
  out_proj_mfma<<<512, 256, 0, stream>>>(o_ws, wob, bo, out);
}